// Round 8
// baseline (415.691 us; speedup 1.0000x reference)
//
#include <hip/hip_runtime.h>

// VQ-VAE quantizer: x [B=32, C=64, T=4096] f32, emb [K=1024, D=64] f32.
// Outputs flat f32: quant_out [B*C*T], codebook_loss [1], commitment_loss [1],
// idx [B*T] (as float).
//
// CORRECTNESS MODEL (validated R2/R4/R5/R6: absmax 3.8e-6 = zero argmin flips):
// checker recomputes reference with numpy f32. d_np = fl(fl(S+e2[k]) - 2*dot)
// (~64) is quantized at ulp(64)=7.6e-6; near-ties are decided by numpy's exact
// rounding. R8 design: bf16 MFMA SCREEN + np-exact rescore of near-ties only.
//   screen: dot~ = MFMA(bf16(x), bf16(e)) fp32-acc; s~ = e2[k] - 2*dot~
//   bound : |s~ - (d_np - S)| <= B_row = 2^-8 * (1/1024) * sum|x_i| + slack
//           (bf16 RTE rel err 2^-9 per operand; MFMA f32-acc err ~3e-7;
//            np big-number compose rounding ~1.6e-5)  -> B ~ 2.5e-4
//   decide: per-row screen top-2 (packed u64: signflip(f32)<<10 | k).
//           If v2 > v1+2B -> screen argmin == np argmin (proof: for any k!=k1,
//           d_np(k)-S >= s~(k)-B >= v2-B > v1+B >= d_np(k1)-S).
//           Else -> FALLBACK: np-exact full scan of all 1024 cands for that
//           row (per-candidate single-acc seq-k fma chain = validated BLAS
//           order; packed-u64 min = value order + first-index tie-break).
//   S, e2 : numpy pairwise_sum of fl(v*v), n=64 (8 accs stride-8, then
//           ((r0+r1)+(r2+r3))+((r4+r5)+(r6+r7))) — np-exact, validated.
// Perf history: R2 453 (remat), R3 1017 (scratch), R4 369 (AGPR shunt),
// R5 828 (spill), R6 325 (s_load plateau), R7 372 (occupancy). Scalar path
// floor ~109us issue but ~250us realized -> move dots to MFMA.

typedef unsigned long long u64;
typedef unsigned short ushortT;
typedef __attribute__((ext_vector_type(8))) short bf8_t;   // 8 bf16 (A/B frag)
typedef __attribute__((ext_vector_type(4))) float f4_t;    // 4 f32  (C/D frag)

#define KCB 1024
#define DD 64
#define BB 32
#define TT 4096
#define BT (BB * TT)
#define NELEM (BB * DD * TT)

#define MROWS 128              // rows per block
#define XSTR 72                // xbf LDS stride (ushorts): 144B = 16-aligned
#define ESTR 72                // ebf LDS stride
#define DSTR 65                // dot LDS stride (floats): (r+c)%32 banking
#define FB_MAX 64

#define WS_LOSS 0
#define WS_E2 64
#define WS_EBF 1088            // float offset; ushort[1024*64] = 128 KB

__device__ __forceinline__ ushortT bf16rte(float f) {
    unsigned u = __float_as_uint(f);
    return (ushortT)((u + 0x7FFFu + ((u >> 16) & 1u)) >> 16);
}
__device__ __forceinline__ unsigned flipf(float f) {
    unsigned u = __float_as_uint(f);
    return (u & 0x80000000u) ? ~u : (u | 0x80000000u);
}
__device__ __forceinline__ float unflipf(unsigned u) {
    return (u & 0x80000000u) ? __uint_as_float(u ^ 0x80000000u)
                             : __uint_as_float(~u);
}

// Phase 0: e2[k] (np-exact pairwise), bf16(emb) table, zero loss accumulator.
__global__ void vq_prep(const float* __restrict__ emb, float* __restrict__ ws) {
#pragma clang fp contract(off)
    int k = blockIdx.x * blockDim.x + threadIdx.x;
    if (k == 0) ws[WS_LOSS] = 0.0f;
    if (k < KCB) {
        const float* e = emb + (size_t)k * DD;
        ushortT* ebf_g = (ushortT*)(ws + WS_EBF);
        float r[8];
#pragma unroll
        for (int j = 0; j < 8; ++j) { float v = e[j]; r[j] = v * v; ebf_g[k * DD + j] = bf16rte(v); }
#pragma unroll
        for (int i = 8; i < 64; i += 8) {
#pragma unroll
            for (int j = 0; j < 8; ++j) { float v = e[i + j]; r[j] += v * v; ebf_g[k * DD + i + j] = bf16rte(v); }
        }
        ws[WS_E2 + k] = ((r[0] + r[1]) + (r[2] + r[3])) + ((r[4] + r[5]) + (r[6] + r[7]));
    }
}

__launch_bounds__(256, 2)
__global__ void vq_main(const float* __restrict__ x, const float* __restrict__ emb,
                        float* __restrict__ out, float* __restrict__ ws) {
#pragma clang fp contract(off)
    const int tid = threadIdx.x;
    const int lane = tid & 63;
    const int w = __builtin_amdgcn_readfirstlane(tid >> 6);   // wave id, SGPR
    const int q = lane >> 4, c15 = lane & 15;

    const int row0 = blockIdx.x * MROWS;        // 128 | 4096 -> b uniform
    const int b = row0 >> 12;
    const int t0 = row0 & (TT - 1);

    __shared__ __align__(16) ushortT xbf[MROWS * XSTR];      // 18.4 KB
    __shared__ __align__(16) ushortT ebf[128 * ESTR];        // 18.4 KB
    __shared__ __align__(16) float dls[MROWS * DSTR];        // 33.3 KB (multi-use)
    __shared__ float Srow[MROWS], Brow[MROWS];
    __shared__ int kwin[MROWS];
    __shared__ u64 rfmin[FB_MAX];
    __shared__ int fbrows[FB_MAX];
    __shared__ int fbcnt;
    __shared__ float bsum;

    const float* e2g = ws + WS_E2;
    const ushortT* ebf_g = (const ushortT*)(ws + WS_EBF);

    if (tid == 0) { fbcnt = 0; bsum = 0.0f; }
    if (tid < FB_MAX) rfmin[tid] = ~0ull;

    // ---- Stage phase: threads<128 own a row (x load, np-exact S, sum|x|,
    // bf16 conversion into xbf); threads>=128 prestage ebf tile 0.
    if (tid < 128) {
        const int r = tid;
        const float* xr = x + (size_t)b * DD * TT + t0 + r;   // dim c at xr[c*TT]
        float rr[8]; float sa = 0.0f;
#pragma unroll
        for (int j = 0; j < 8; ++j) {
            float v = xr[(size_t)j * TT];
            rr[j] = v * v; sa += fabsf(v);
            xbf[r * XSTR + j] = bf16rte(v);
        }
#pragma unroll
        for (int i = 8; i < 64; i += 8) {
#pragma unroll
            for (int j = 0; j < 8; ++j) {
                float v = xr[(size_t)(i + j) * TT];
                rr[j] += v * v; sa += fabsf(v);
                xbf[r * XSTR + i + j] = bf16rte(v);
            }
        }
        Srow[r] = ((rr[0] + rr[1]) + (rr[2] + rr[3])) + ((rr[4] + rr[5]) + (rr[6] + rr[7]));
        Brow[r] = __builtin_fmaf(4.2e-6f, sa, 3.0e-5f);       // screen error bound
    } else {
        const int n = tid - 128;                               // cand 0..127 of tile 0
        const uint4* s0 = (const uint4*)(ebf_g + (size_t)n * DD);
        uint4* d0 = (uint4*)(ebf + n * ESTR);
#pragma unroll
        for (int j = 0; j < 8; ++j) d0[j] = s0[j];
    }
    __syncthreads();

    // ---- Screen: 8 e-tiles x (2 halves of 64 cands). MFMA 16x16x32_bf16.
    // Wave w owns rows [32w, 32w+32). Per-thread screen top-2 across all k.
    u64 p1 = ~0ull, p2 = ~0ull;
    const int sr = tid & 127, cs = (tid >> 7) * 32;            // scan row / col seg

    for (int T = 0; T < 8; ++T) {
        if (T > 0) {
            __syncthreads();   // prev scan done; safe to overwrite ebf
            const int n = tid >> 1, dh = (tid & 1) * 32;
            const uint4* sp = (const uint4*)(ebf_g + (size_t)(T * 128 + n) * DD + dh);
            uint4* dp = (uint4*)(ebf + n * ESTR + dh);
#pragma unroll
            for (int j = 0; j < 4; ++j) dp[j] = sp[j];
        }
        __syncthreads();

        for (int h = 0; h < 2; ++h) {
            f4_t acc[2][4];
#pragma unroll
            for (int ms = 0; ms < 2; ++ms)
#pragma unroll
                for (int nn = 0; nn < 4; ++nn) acc[ms][nn] = (f4_t){0.f, 0.f, 0.f, 0.f};

#pragma unroll
            for (int s = 0; s < 2; ++s) {                       // k-steps of 32
                bf8_t a0 = *(const bf8_t*)&xbf[(32 * w + c15) * XSTR + 32 * s + 8 * q];
                bf8_t a1 = *(const bf8_t*)&xbf[(32 * w + 16 + c15) * XSTR + 32 * s + 8 * q];
#pragma unroll
                for (int nn = 0; nn < 4; ++nn) {
                    bf8_t bfr = *(const bf8_t*)&ebf[(h * 64 + nn * 16 + c15) * ESTR + 32 * s + 8 * q];
                    acc[0][nn] = __builtin_amdgcn_mfma_f32_16x16x32_bf16(a0, bfr, acc[0][nn], 0, 0, 0);
                    acc[1][nn] = __builtin_amdgcn_mfma_f32_16x16x32_bf16(a1, bfr, acc[1][nn], 0, 0, 0);
                }
            }
            // dump dots: D layout col=lane&15 (n), row=quad*4+reg (m)  [m89]
#pragma unroll
            for (int ms = 0; ms < 2; ++ms)
#pragma unroll
                for (int nn = 0; nn < 4; ++nn)
#pragma unroll
                    for (int rg = 0; rg < 4; ++rg)
                        dls[(32 * w + 16 * ms + 4 * q + rg) * DSTR + nn * 16 + c15] = acc[ms][nn][rg];
            __syncthreads();

            // scan: thread covers (row sr, cols [cs,cs+32)); e2 via uniform s_load
            const int kb = T * 128 + h * 64 + cs;
#pragma unroll 4
            for (int c = 0; c < 32; ++c) {
                float dot = dls[sr * DSTR + cs + c];
                float sv = __builtin_fmaf(-2.0f, dot, e2g[kb + c]);
                u64 pk = ((u64)flipf(sv) << 10) | (unsigned)(kb + c);
                if (pk < p1) { p2 = p1; p1 = pk; } else if (pk < p2) { p2 = pk; }
            }
            __syncthreads();   // scan done before next dump overwrites dls
        }
    }

    // ---- Merge the two col-segments per row; band test; fallback collection.
    u64* mergeP = (u64*)dls;                     // overlay (dls free after scans)
    mergeP[tid] = p1; mergeP[256 + tid] = p2;
    __syncthreads();
    if (tid < 128) {
        u64 a1 = p1, a2 = p2;
        u64 b1 = mergeP[tid + 128], b2 = mergeP[256 + tid + 128];
        u64 m1 = a1 < b1 ? a1 : b1;
        u64 mx = a1 > b1 ? a1 : b1;
        u64 mn2 = a2 < b2 ? a2 : b2;
        u64 m2 = mx < mn2 ? mx : mn2;
        float v1 = unflipf((unsigned)(m1 >> 10));
        float v2 = unflipf((unsigned)(m2 >> 10));
        kwin[tid] = (int)(m1 & 1023u);
        if (v2 <= v1 + 2.0f * Brow[tid]) {       // near-tie: needs np-exact rescan
            int s = atomicAdd(&fbcnt, 1);
            if (s < FB_MAX) fbrows[s] = tid;
        }
    }
    __syncthreads();

    // ---- Fallback: np-exact full scan for near-tie rows (~11%).
    const int cnt = min(fbcnt, FB_MAX);
    if (cnt > 0) {
        float* efs = dls;                        // 64*65 = 4160 floats
        float* xfb = dls + 4160;                 // 64*64 = 4096 floats
        for (int fi = w; fi < cnt; fi += 4) {    // wave stages its rows' x (f32)
            int r = fbrows[fi];
            xfb[fi * 64 + lane] = x[(size_t)b * DD * TT + (size_t)lane * TT + t0 + r];
        }
        for (int T2 = 0; T2 < 16; ++T2) {        // 16 tiles of 64 cands
            __syncthreads();
            {   // stage e f32 tile: thread covers cand tid>>2, dims [(tid&3)*16,+16)
                const int cc = tid >> 2, d0 = (tid & 3) * 16;
                const float4* sp = (const float4*)(emb + (size_t)(T2 * 64 + cc) * DD + d0);
                float* dp = efs + cc * 65 + d0;
#pragma unroll
                for (int j = 0; j < 4; ++j) *(float4*)(dp + 4 * j) = sp[j];
            }
            __syncthreads();
            for (int fi = w; fi < cnt; fi += 4) {
                int r = fbrows[fi];
                float acc = 0.0f;
#pragma unroll
                for (int i = 0; i < 64; ++i)     // np-exact: seq-k single-acc chain
                    acc = __builtin_fmaf(efs[lane * 65 + i], xfb[fi * 64 + i], acc);
                float tt = Srow[r] + e2g[T2 * 64 + lane];     // fl(S + e2)
                float sv = __builtin_fmaf(-2.0f, acc, tt);    // fl(tt - 2*dot)
                u64 pk = ((u64)flipf(sv) << 10) | (unsigned)(T2 * 64 + lane);
#pragma unroll
                for (int dl = 32; dl > 0; dl >>= 1) {
                    u64 o = __shfl_xor(pk, dl);
                    pk = o < pk ? o : pk;
                }
                if (lane == 0) { u64 c0 = rfmin[fi]; rfmin[fi] = pk < c0 ? pk : c0; }
            }
        }
        __syncthreads();
        if (tid < cnt) kwin[fbrows[tid]] = (int)(rfmin[tid] & 1023u);
    }
    __syncthreads();

    // ---- Epilogue: idx, quant_out = emb[kwin] (L2-resident gather), loss.
    if (tid < 128) out[NELEM + 2 + row0 + tid] = (float)kwin[tid];

    const int r = tid & 127, c0 = (tid >> 7) * 32;
    const int kw = kwin[r];
    const float* eqr = emb + (size_t)kw * DD;
    float lsum = 0.0f;
#pragma unroll 8
    for (int i = 0; i < 32; ++i) {
        int c = c0 + i;
        size_t o = (size_t)b * DD * TT + (size_t)c * TT + t0 + r;
        float qv = eqr[c];
        float xv = x[o];
        out[o] = qv;
        float a = qv - xv;
        lsum = __builtin_fmaf(a, a, lsum);
    }
#pragma unroll
    for (int off = 32; off > 0; off >>= 1) lsum += __shfl_down(lsum, off);
    if (lane == 0) atomicAdd(&bsum, lsum);
    __syncthreads();
    if (tid == 0) atomicAdd(ws + WS_LOSS, bsum);
}

__global__ void vq_finalize(const float* __restrict__ ws, float* __restrict__ out) {
    if (threadIdx.x == 0 && blockIdx.x == 0) {
        float M = ws[WS_LOSS] / (float)NELEM;
        out[NELEM + 0] = M;           // codebook_loss
        out[NELEM + 1] = 0.25f * M;   // commitment_loss = BETA * same mean
    }
}

extern "C" void kernel_launch(void* const* d_in, const int* in_sizes, int n_in,
                              void* d_out, int out_size, void* d_ws, size_t ws_size,
                              hipStream_t stream) {
    const float* x = (const float*)d_in[0];
    const float* emb = (const float*)d_in[1];
    float* out = (float*)d_out;
    float* ws = (float*)d_ws;

    vq_prep<<<KCB / 256, 256, 0, stream>>>(emb, ws);
    vq_main<<<BT / MROWS, 256, 0, stream>>>(x, emb, out, ws);
    vq_finalize<<<1, 64, 0, stream>>>(ws, out);
}

// Round 9
// 243.912 us; speedup vs baseline: 1.7043x; 1.7043x over previous
//
#include <hip/hip_runtime.h>

// VQ-VAE quantizer: x [B=32, C=64, T=4096] f32, emb [K=1024, D=64] f32.
// Outputs flat f32: quant_out [B*C*T], codebook_loss [1], commitment_loss [1],
// idx [B*T] (as float).
//
// CORRECTNESS MODEL (validated R2..R8): checker recomputes the reference with
// numpy f32. d_np(k) = RN( fl(S+e2[k]) - 2*g_k ), g_k = sequential-k single-acc
// FMA chain (BLAS). d~64 -> grid ulp(64)=7.6e-6; near-ties decided by numpy's
// exact rounding. R9 screen: split-bf16 MFMA (x=xh+xl, e=eh+el; passes
// xh*eh + xh*el + xl*eh, f32 acc) -> |dot~ - g_k| <= ~1.5e-6 =: delta.
// Scan computes u_k = fl(fl(S+e2[k]) - 2*dot~) with np-exact fl(S+e2[k]).
// Certify screen winner iff v2 - v1 > BAND >= 2*delta + 2*ulp: then
// u-order => pre-round order => (RN monotone, gap>ulp) strict d_np order.
// Else FALLBACK (np-exact full 1024-cand rescan, packed-u64 (flip(d)<<10|k)
// min = value order + first-index tie-break). S, e2: numpy pairwise_sum of
// fl(v*v), n=64 (8 accs stride-8, ((r0+r1)+(r2+r3))+((r4+r5)+(r6+r7))).
// DO NOT change fallback chain arithmetic/order or S/e2 pairwise pattern.
//
// Perf history: R2 453 (remat) / R3 1017 (scratch) / R4 369 (AGPR shunt) /
// R5 828 (spill) / R6 325 (s_load plateau) / R7 372 (occupancy) /
// R8 359 (MFMA screen, but 7.3M LDS bank conflicts (XSTR=72 frag loads),
//         72.7KB LDS -> 2 blk/CU, ~80 barriers). R9 fixes: fragment-order
// LDS (conflict-free, emb pre-swizzled in prep -> staging = uint4 memcpy),
// wave-private dump slabs (no dump/scan barriers), 64 rows/block (49KB LDS
// -> 3 blk/CU), split-bf16 (fallback 11% -> ~1%).

typedef unsigned long long u64;
typedef unsigned short u16;
typedef __attribute__((ext_vector_type(8))) short bf8_t;   // 8 bf16 (A/B frag)
typedef __attribute__((ext_vector_type(4))) float f4_t;    // 4 f32  (C/D frag)

#define KCB 1024
#define DD 64
#define BB 32
#define TT 4096
#define BT (BB * TT)
#define NELEM (BB * DD * TT)

#define RPB 64                 // rows per block
#define NT 16                  // emb tiles
#define TC 64                  // candidates per tile
#define FB_MAX 16
#define BAND 4e-5f             // 2*delta + 2*ulp(128) with 2x margin

#define WS_LOSS 0
#define WS_E2 64
#define WS_EH 2048             // float offset: eh frag table (64Ki u16 = 128KB)
#define WS_EL 34816            // el frag table

__device__ __forceinline__ u16 bf16rte(float f) {
    unsigned u = __float_as_uint(f);
    return (u16)((u + 0x7FFFu + ((u >> 16) & 1u)) >> 16);
}
__device__ __forceinline__ unsigned flipf(float f) {
    unsigned u = __float_as_uint(f);
    return (u & 0x80000000u) ? ~u : (u | 0x80000000u);
}
// frag-order index: cand n (within 64-tile), dim d -> ushort index in 8KB tile
__device__ __forceinline__ int fragidx(int n, int d) {
    return 1024 * (n >> 4) + 512 * (d >> 5) + 128 * ((d >> 3) & 3)
         + 8 * (n & 15) + (d & 7);
}

// Phase 0: np-exact e2[k]; split-bf16 emb tables in MFMA fragment order.
__global__ void vq_prep(const float* __restrict__ emb, float* __restrict__ ws) {
#pragma clang fp contract(off)
    int k = blockIdx.x * blockDim.x + threadIdx.x;
    if (k == 0) ws[WS_LOSS] = 0.0f;
    if (k >= KCB) return;
    const float* e = emb + (size_t)k * DD;
    u16* ehg = (u16*)(ws + WS_EH) + 4096 * (k >> 6);
    u16* elg = (u16*)(ws + WS_EL) + 4096 * (k >> 6);
    const int n = k & 63;
    float r[8];
#pragma unroll
    for (int i = 0; i < 64; i += 8) {
#pragma unroll
        for (int j = 0; j < 8; ++j) {
            float v = e[i + j];
            if (i == 0) r[j] = v * v; else r[j] += v * v;
            u16 hb = bf16rte(v);
            float hv = __uint_as_float((unsigned)hb << 16);
            u16 lb = bf16rte(v - hv);          // v-hv exact (Sterbenz)
            int ia = fragidx(n, i + j);
            ehg[ia] = hb; elg[ia] = lb;
        }
    }
    ws[WS_E2 + k] = ((r[0] + r[1]) + (r[2] + r[3])) + ((r[4] + r[5]) + (r[6] + r[7]));
}

__launch_bounds__(256, 3)
__global__ void vq_main(const float* __restrict__ x, const float* __restrict__ emb,
                        float* __restrict__ out, float* __restrict__ ws) {
#pragma clang fp contract(off)
    const int tid = threadIdx.x;
    const int lane = tid & 63;
    const int w = __builtin_amdgcn_readfirstlane(tid >> 6);
    const int l15 = lane & 15, h4 = lane >> 4;

    const int row0 = blockIdx.x * RPB;          // 64 | 4096 -> b uniform
    const int b = row0 >> 12;
    const int t0 = row0 & (TT - 1);

    // Arena: [ehT 8K][elT 8K][xhT 8K][xlT 8K][dls 9216B] ; fallback overlays
    // efs(16640B)+xfb(4160B) onto the first 24KB (dead after screen).
    __shared__ __align__(16) char arena[32768 + 9216];
    u16* ehT = (u16*)arena;
    u16* elT = (u16*)(arena + 8192);
    u16* xhT = (u16*)(arena + 16384);
    u16* xlT = (u16*)(arena + 24576);
    float* dls = (float*)(arena + 32768);       // 4 wave slabs of 16x36
    float* efs = (float*)arena;                 // fallback: 64 cands x 65 f32
    float* xfb = (float*)(arena + 16640);       // fallback: 16 rows x 65 f32

    __shared__ float e2l[KCB];                  // 4KB, np-exact e2
    __shared__ float Srow[RPB];
    __shared__ float mv1[4 * RPB], mk1[4 * RPB], mv2[4 * RPB];
    __shared__ int kwin[RPB];
    __shared__ int fbrows[FB_MAX];
    __shared__ int fbcnt;
    __shared__ float bsum;

    if (tid == 0) { fbcnt = 0; bsum = 0.0f; }
#pragma unroll
    for (int i = tid; i < KCB; i += 256) e2l[i] = ws[WS_E2 + i];

    // stage emb tile 0 (pure linear copy; tables pre-swizzled to frag order)
    {
        const uint4* se = (const uint4*)(ws + WS_EH);
        const uint4* sl = (const uint4*)(ws + WS_EL);
        ((uint4*)ehT)[tid] = se[tid]; ((uint4*)ehT)[tid + 256] = se[tid + 256];
        ((uint4*)elT)[tid] = sl[tid]; ((uint4*)elT)[tid + 256] = sl[tid + 256];
    }

    // x stage: thread r<64 owns a row — np-exact S + split-bf16 frag writes.
    if (tid < RPB) {
        const int r = tid;
        const float* xr = x + (size_t)b * DD * TT + t0 + r;
        float rr[8];
#pragma unroll
        for (int i = 0; i < 64; i += 8) {
#pragma unroll
            for (int j = 0; j < 8; ++j) {
                float v = xr[(size_t)(i + j) * TT];
                if (i == 0) rr[j] = v * v; else rr[j] += v * v;
                u16 hb = bf16rte(v);
                float hv = __uint_as_float((unsigned)hb << 16);
                u16 lb = bf16rte(v - hv);
                int ia = fragidx(r, i + j);
                xhT[ia] = hb; xlT[ia] = lb;
            }
        }
        Srow[r] = ((rr[0] + rr[1]) + (rr[2] + rr[3])) + ((rr[4] + rr[5]) + (rr[6] + rr[7]));
    }
    __syncthreads();

    // A-frags: rows 16w..16w+16, loaded once (x frags static across tiles).
    bf8_t ah0 = *(const bf8_t*)&xhT[1024 * w + 8 * lane];
    bf8_t ah1 = *(const bf8_t*)&xhT[1024 * w + 512 + 8 * lane];
    bf8_t al0 = *(const bf8_t*)&xlT[1024 * w + 8 * lane];
    bf8_t al1 = *(const bf8_t*)&xlT[1024 * w + 512 + 8 * lane];

    const float Sv = Srow[16 * w + l15];        // row this thread scans
    float v1 = 3.4e38f, v2 = 3.4e38f, k1 = 0.0f;

    const int slab = w * 576;
#pragma unroll 1
    for (int T = 0; T < NT; ++T) {
#pragma unroll
        for (int h = 0; h < 2; ++h) {
            // MFMA: rows 16w+ x cols [32h,32h+32) of tile T; 3 passes.
#pragma unroll
            for (int nn = 0; nn < 2; ++nn) {
                const int cg = 2 * h + nn;
                bf8_t bh0 = *(const bf8_t*)&ehT[1024 * cg + 8 * lane];
                bf8_t bh1 = *(const bf8_t*)&ehT[1024 * cg + 512 + 8 * lane];
                bf8_t bl0 = *(const bf8_t*)&elT[1024 * cg + 8 * lane];
                bf8_t bl1 = *(const bf8_t*)&elT[1024 * cg + 512 + 8 * lane];
                f4_t acc = (f4_t){0.f, 0.f, 0.f, 0.f};
                acc = __builtin_amdgcn_mfma_f32_16x16x32_bf16(ah0, bh0, acc, 0, 0, 0);
                acc = __builtin_amdgcn_mfma_f32_16x16x32_bf16(ah0, bl0, acc, 0, 0, 0);
                acc = __builtin_amdgcn_mfma_f32_16x16x32_bf16(al0, bh0, acc, 0, 0, 0);
                acc = __builtin_amdgcn_mfma_f32_16x16x32_bf16(ah1, bh1, acc, 0, 0, 0);
                acc = __builtin_amdgcn_mfma_f32_16x16x32_bf16(ah1, bl1, acc, 0, 0, 0);
                acc = __builtin_amdgcn_mfma_f32_16x16x32_bf16(al1, bh1, acc, 0, 0, 0);
                // D: col=16nn+c15, row-in-16 = 4q+rg [m89]; wave-private slab
#pragma unroll
                for (int rg = 0; rg < 4; ++rg)
                    dls[slab + (4 * h4 + rg) * 36 + 16 * nn + l15] = acc[rg];
            }
            // scan own slab: row 16w+l15, cols [8*h4, 8*h4+8) of this dump
            const int kb = T * 64 + 32 * h + 8 * h4;
            const float kbf = (float)kb;
            const float4 d0 = *(const float4*)(dls + slab + l15 * 36 + h4 * 8);
            const float4 d1 = *(const float4*)(dls + slab + l15 * 36 + h4 * 8 + 4);
            float dv[8] = {d0.x, d0.y, d0.z, d0.w, d1.x, d1.y, d1.z, d1.w};
#pragma unroll
            for (int c = 0; c < 8; ++c) {
                float ck = Sv + e2l[kb + c];               // np-exact fl(S+e2)
                float u = __builtin_fmaf(-2.0f, dv[c], ck);
                bool lt = u < v1;
                float spill = lt ? v1 : u;
                v2 = fminf(v2, spill);
                k1 = lt ? (kbf + (float)c) : k1;
                v1 = fminf(v1, u);
            }
        }
        if (T < NT - 1) {
            __syncthreads();     // all waves done with tile T
            const uint4* se = (const uint4*)(ws + WS_EH) + (T + 1) * 512;
            const uint4* sl = (const uint4*)(ws + WS_EL) + (T + 1) * 512;
            ((uint4*)ehT)[tid] = se[tid]; ((uint4*)ehT)[tid + 256] = se[tid + 256];
            ((uint4*)elT)[tid] = sl[tid]; ((uint4*)elT)[tid + 256] = sl[tid + 256];
            __syncthreads();
        }
    }

    // merge 4 col-segments per row; band test; fallback collection
    const int mrow = 16 * w + l15;
    mv1[h4 * RPB + mrow] = v1; mk1[h4 * RPB + mrow] = k1; mv2[h4 * RPB + mrow] = v2;
    __syncthreads();
    if (tid < RPB) {
        float g1 = 3.4e38f, g2 = 3.4e38f, gk = 0.0f;
#pragma unroll
        for (int s = 0; s < 4; ++s) {
            float a = mv1[s * RPB + tid], ka = mk1[s * RPB + tid], b2 = mv2[s * RPB + tid];
            bool lt = a < g1;
            float spill = lt ? g1 : a;
            g2 = fminf(g2, spill);
            g2 = fminf(g2, b2);
            gk = lt ? ka : gk;
            g1 = fminf(g1, a);
        }
        kwin[tid] = (int)gk;
        if (g2 <= g1 + BAND) {                  // near-tie (incl. exact ties)
            int s = atomicAdd(&fbcnt, 1);
            if (s < FB_MAX) fbrows[s] = tid;
        }
    }
    __syncthreads();

    // FALLBACK: np-exact full rescan for near-tie rows (~1%). Block-uniform skip.
    const int cnt = min(fbcnt, FB_MAX);
    if (cnt > 0) {
        for (int i = tid; i < cnt * 64; i += 256) {
            int fi = i >> 6, l = i & 63;
            xfb[fi * 65 + l] = x[(size_t)b * DD * TT + (size_t)l * TT + t0 + fbrows[fi]];
        }
        u64 pmin[4] = {~0ull, ~0ull, ~0ull, ~0ull};
#pragma unroll 1
        for (int T2 = 0; T2 < NT; ++T2) {
            __syncthreads();
            {   // stage f32 e tile (stride 65: 2-way-free chain reads)
                const int n = tid >> 2, qd = (tid & 3) * 16;
                const float* sp = emb + (size_t)(T2 * 64 + n) * DD + qd;
                float* dp = efs + n * 65 + qd;
#pragma unroll
                for (int j = 0; j < 16; ++j) dp[j] = sp[j];
            }
            __syncthreads();
#pragma unroll
            for (int sl = 0; sl < 4; ++sl) {
                const int fi = w + 4 * sl;
                if (fi < cnt) {
                    const int rr = fbrows[fi];
                    float acc = 0.0f;
#pragma unroll
                    for (int i = 0; i < 64; ++i)   // np-exact seq-k chain
                        acc = __builtin_fmaf(efs[lane * 65 + i], xfb[fi * 65 + i], acc);
                    float ck = Srow[rr] + e2l[T2 * 64 + lane];
                    float u = __builtin_fmaf(-2.0f, acc, ck);
                    u64 pk = ((u64)flipf(u) << 10) | (unsigned)(T2 * 64 + lane);
                    pmin[sl] = pmin[sl] < pk ? pmin[sl] : pk;
                }
            }
        }
#pragma unroll
        for (int sl = 0; sl < 4; ++sl) {
            const int fi = w + 4 * sl;
            if (fi < cnt) {
                u64 pk = pmin[sl];
#pragma unroll
                for (int d = 32; d > 0; d >>= 1) {
                    u64 o = __shfl_xor(pk, d);
                    pk = o < pk ? o : pk;
                }
                if (lane == 0) kwin[fbrows[fi]] = (int)(pk & 1023u);
            }
        }
    }
    __syncthreads();

    // Epilogue: idx, quant_out = emb[kwin] (exact), loss sum.
    if (tid < RPB) out[NELEM + 2 + row0 + tid] = (float)kwin[tid];

    const int r = tid & 63, c0 = (tid >> 6) * 16;
    const int kw = kwin[r];
    const float* eqr = emb + (size_t)kw * DD;
    float lsum = 0.0f;
#pragma unroll
    for (int i = 0; i < 16; ++i) {
        int c = c0 + i;
        size_t o = (size_t)b * DD * TT + (size_t)c * TT + t0 + r;
        float qv = eqr[c];
        float xv = x[o];
        out[o] = qv;
        float a = qv - xv;
        lsum = __builtin_fmaf(a, a, lsum);
    }
#pragma unroll
    for (int off = 32; off > 0; off >>= 1) lsum += __shfl_down(lsum, off);
    if (lane == 0) atomicAdd(&bsum, lsum);
    __syncthreads();
    if (tid == 0) atomicAdd(ws + WS_LOSS, bsum);
}

__global__ void vq_finalize(const float* __restrict__ ws, float* __restrict__ out) {
    if (threadIdx.x == 0 && blockIdx.x == 0) {
        float M = ws[WS_LOSS] / (float)NELEM;
        out[NELEM + 0] = M;           // codebook_loss
        out[NELEM + 1] = 0.25f * M;   // commitment_loss = BETA * same mean
    }
}

extern "C" void kernel_launch(void* const* d_in, const int* in_sizes, int n_in,
                              void* d_out, int out_size, void* d_ws, size_t ws_size,
                              hipStream_t stream) {
    const float* x = (const float*)d_in[0];
    const float* emb = (const float*)d_in[1];
    float* out = (float*)d_out;
    float* ws = (float*)d_ws;

    vq_prep<<<KCB / 256, 256, 0, stream>>>(emb, ws);
    vq_main<<<BT / RPB, 256, 0, stream>>>(x, emb, out, ws);
    vq_finalize<<<1, 64, 0, stream>>>(ws, out);
}

// Round 10
// 204.101 us; speedup vs baseline: 2.0367x; 1.1951x over previous
//
#include <hip/hip_runtime.h>

// VQ-VAE quantizer: x [B=32, C=64, T=4096] f32, emb [K=1024, D=64] f32.
// Outputs flat f32: quant_out [B*C*T], codebook_loss [1], commitment_loss [1],
// idx [B*T] (as float).
//
// CORRECTNESS MODEL (validated R2..R9): checker recomputes the reference with
// numpy f32. d_np(k) = RN( fl(S+e2[k]) - 2*g_k ), g_k = sequential-k single-acc
// FMA chain (BLAS). d~64 -> grid ulp(64)=7.6e-6; near-ties decided by numpy's
// exact rounding. Screen: split-bf16 MFMA (x=xh+xl, e=eh+el; xh*eh + xh*el +
// xl*eh, f32 acc) -> |dot~ - g_k| <= ~1.5e-6. Scan u_k = fl(fl(S+e2[k])-2dot~)
// with np-exact fl(S+e2[k]). Certify winner iff v2-v1 > BAND (4e-5); else
// np-exact full rescan (packed-u64 (flip(d)<<10|k) min = value order +
// first-index tie-break). S,e2: numpy pairwise_sum of fl(v*v), n=64
// (8 accs stride-8, ((r0+r1)+(r2+r3))+((r4+r5)+(r6+r7))).
// DO NOT change fallback chain arithmetic/order or S/e2 pairwise pattern.
//
// Perf: R2 453 / R3 1017 / R4 369 / R5 828 / R6 325 / R7 372 / R8 359 /
// R9 186+58 tail (LDS dump/scan round-trip, 4.8M conflicts, 25% occ, slow
// prep). R10: in-register scan (C-layout rows scanned in VGPRs, shfl-xor
// merge), B-frags DIRECT from global frag-order tables (no k-loop barriers),
// RPB=128 (halves B traffic), parallel prep.

typedef unsigned long long u64;
typedef unsigned short u16;
typedef __attribute__((ext_vector_type(8))) short bf8_t;   // 8 bf16 (A/B frag)
typedef __attribute__((ext_vector_type(4))) float f4_t;    // 4 f32  (C/D frag)

#define KCB 1024
#define DD 64
#define BB 32
#define TT 4096
#define BT (BB * TT)
#define NELEM (BB * DD * TT)

#define RPB 128                // rows per block
#define NT 16                  // emb tiles (64 cands each)
#define FB_MAX 48
#define BAND 4e-5f

#define WS_LOSS 0
#define WS_E2 64
#define WS_EH 2048             // float offset: eh frag table (64Ki u16 = 128KB)
#define WS_EL 34816            // el frag table

static __device__ __forceinline__ u16 bf16rte(float f) {
    unsigned u = __float_as_uint(f);
    return (u16)((u + 0x7FFFu + ((u >> 16) & 1u)) >> 16);
}
static __device__ __forceinline__ unsigned flipf(float f) {
    unsigned u = __float_as_uint(f);
    return (u & 0x80000000u) ? ~u : (u | 0x80000000u);
}
// frag-order index within a 64-cand tile: cand n, dim d -> u16 index
static __device__ __forceinline__ int fragidx(int n, int d) {
    return 1024 * (n >> 4) + 512 * (d >> 5) + 128 * ((d >> 3) & 3)
         + 8 * (n & 15) + (d & 7);
}

// Prep: parallel (256 blocks x 256 thr; block owns 4 cands). np-exact e2 via
// LDS pairwise; split-bf16 frag-order tables; coalesced loads.
__global__ void vq_prep(const float* __restrict__ emb, float* __restrict__ ws) {
#pragma clang fp contract(off)
    const int tid = threadIdx.x;
    const int kl = tid >> 6, d = tid & 63;
    const int k = blockIdx.x * 4 + kl;
    if (blockIdx.x == 0 && tid == 0) ws[WS_LOSS] = 0.0f;
    __shared__ float sq[4][64];
    __shared__ float rsh[4][8];
    float v = emb[(size_t)k * DD + d];
    u16 hb = bf16rte(v);
    float hv = __uint_as_float((unsigned)hb << 16);
    u16 lb = bf16rte(v - hv);                  // v-hv exact (Sterbenz)
    u16* ehg = (u16*)(ws + WS_EH) + 4096 * (k >> 6);
    u16* elg = (u16*)(ws + WS_EL) + 4096 * (k >> 6);
    const int ia = fragidx(k & 63, d);
    ehg[ia] = hb; elg[ia] = lb;
    sq[kl][d] = v * v;                         // fl(e*e) individually rounded
    __syncthreads();
    if (tid < 32) {
        const int g = tid >> 3, j = tid & 7;
        float r = sq[g][j];
#pragma unroll
        for (int i = 1; i < 8; ++i) r += sq[g][8 * i + j];   // i ascending
        rsh[g][j] = r;
    }
    __syncthreads();
    if (tid < 4) {
        const float* r = rsh[tid];
        ws[WS_E2 + blockIdx.x * 4 + tid] =
            ((r[0] + r[1]) + (r[2] + r[3])) + ((r[4] + r[5]) + (r[6] + r[7]));
    }
}

__launch_bounds__(256, 4)
__global__ void vq_main(const float* __restrict__ x, const float* __restrict__ emb,
                        float* __restrict__ out, float* __restrict__ ws) {
#pragma clang fp contract(off)
    const int tid = threadIdx.x;
    const int lane = tid & 63;
    const int w = __builtin_amdgcn_readfirstlane(tid >> 6);
    const int l15 = lane & 15, q = lane >> 4;

    const int row0 = blockIdx.x * RPB;          // 128 | 4096 -> b uniform
    const int b = row0 >> 12;
    const int t0 = row0 & (TT - 1);

    // Arena: xhT 16K + xlT 16K (x split-bf16 frag tables; dead after A-frag
    // loads). Fallback overlays efs (64x65 f32 = 16640B) + xfb (48x65 f32).
    __shared__ __align__(16) char arena[32768];
    u16* xhT = (u16*)arena;
    u16* xlT = (u16*)(arena + 16384);
    float* efs = (float*)arena;
    float* xfb = (float*)(arena + 16640);

    __shared__ float e2l[KCB];                  // np-exact e2, 4KB
    __shared__ float Srow[RPB];
    __shared__ int kwin[RPB];
    __shared__ int fbrows[FB_MAX];
    __shared__ int fbcnt;
    __shared__ float bsum;

    if (tid == 0) { fbcnt = 0; bsum = 0.0f; }
#pragma unroll
    for (int i = tid; i < KCB; i += 256) e2l[i] = ws[WS_E2 + i];

    // x stage: thread r<128 owns a row — np-exact S + split-bf16 frag writes.
    if (tid < RPB) {
        const int r = tid;
        const float* xr = x + (size_t)b * DD * TT + t0 + r;
        const int gb = 1024 * (r >> 4);
        float rr[8];
#pragma unroll
        for (int i = 0; i < 64; i += 8) {
#pragma unroll
            for (int j = 0; j < 8; ++j) {
                float v = xr[(size_t)(i + j) * TT];
                if (i == 0) rr[j] = v * v; else rr[j] += v * v;
                u16 hb = bf16rte(v);
                float hv = __uint_as_float((unsigned)hb << 16);
                u16 lb = bf16rte(v - hv);
                const int ia = gb + fragidx(r & 15, i + j);
                xhT[ia] = hb; xlT[ia] = lb;
            }
        }
        Srow[r] = ((rr[0] + rr[1]) + (rr[2] + rr[3])) + ((rr[4] + rr[5]) + (rr[6] + rr[7]));
    }
    __syncthreads();

    // A-frags: wave w owns row-groups 2w, 2w+1 (32 rows); loaded once.
    bf8_t ah[2][2], al[2][2];
#pragma unroll
    for (int g = 0; g < 2; ++g) {
        const int gg = 2 * w + g;
        ah[g][0] = *(const bf8_t*)&xhT[1024 * gg + 8 * lane];
        ah[g][1] = *(const bf8_t*)&xhT[1024 * gg + 512 + 8 * lane];
        al[g][0] = *(const bf8_t*)&xlT[1024 * gg + 8 * lane];
        al[g][1] = *(const bf8_t*)&xlT[1024 * gg + 512 + 8 * lane];
    }
    float Sv[8];
#pragma unroll
    for (int g = 0; g < 2; ++g)
#pragma unroll
        for (int rg = 0; rg < 4; ++rg)
            Sv[4 * g + rg] = Srow[32 * w + 16 * g + 4 * q + rg];

    // In-register scan state: thread owns 8 rows (4q+rg in each group), cols
    // congruent to l15 (mod 16). All indices compile-time after unroll.
    float v1[8], v2[8], kf[8];
#pragma unroll
    for (int s = 0; s < 8; ++s) { v1[s] = 3.4e38f; v2[s] = 3.4e38f; kf[s] = 0.0f; }

    const u16* ehg = (const u16*)(ws + WS_EH);
    const u16* elg = (const u16*)(ws + WS_EL);

    // K-loop: NO barriers. B-frags direct from global frag-order tables
    // (1KB coalesced dwordx4 per load, L2-resident 256KB total).
#pragma unroll 1
    for (int T = 0; T < NT; ++T) {
#pragma unroll
        for (int cg = 0; cg < 4; ++cg) {
            const int kb = 64 * T + 16 * cg;
            const u16* bhp = ehg + 4096 * T + 1024 * cg;
            const u16* blp = elg + 4096 * T + 1024 * cg;
            bf8_t bh0 = *(const bf8_t*)&bhp[8 * lane];
            bf8_t bh1 = *(const bf8_t*)&bhp[512 + 8 * lane];
            bf8_t bl0 = *(const bf8_t*)&blp[8 * lane];
            bf8_t bl1 = *(const bf8_t*)&blp[512 + 8 * lane];
            const float e2v = e2l[kb + l15];       // 16 addrs, 4-way broadcast
            const float kcol = (float)(kb + l15);
#pragma unroll
            for (int g = 0; g < 2; ++g) {
                f4_t acc = (f4_t){0.f, 0.f, 0.f, 0.f};
                acc = __builtin_amdgcn_mfma_f32_16x16x32_bf16(ah[g][0], bh0, acc, 0, 0, 0);
                acc = __builtin_amdgcn_mfma_f32_16x16x32_bf16(ah[g][0], bl0, acc, 0, 0, 0);
                acc = __builtin_amdgcn_mfma_f32_16x16x32_bf16(al[g][0], bh0, acc, 0, 0, 0);
                acc = __builtin_amdgcn_mfma_f32_16x16x32_bf16(ah[g][1], bh1, acc, 0, 0, 0);
                acc = __builtin_amdgcn_mfma_f32_16x16x32_bf16(ah[g][1], bl1, acc, 0, 0, 0);
                acc = __builtin_amdgcn_mfma_f32_16x16x32_bf16(al[g][1], bh1, acc, 0, 0, 0);
                // D: col=lane&15, row-in-16 = 4q+rg  [m89; R8/R9-validated]
#pragma unroll
                for (int rg = 0; rg < 4; ++rg) {
                    const int s = 4 * g + rg;
                    float ck = Sv[s] + e2v;                    // np-exact fl(S+e2)
                    float u = __builtin_fmaf(-2.0f, acc[rg], ck);
                    bool lt = u < v1[s];                       // strict: first-min
                    float sp = lt ? v1[s] : u;
                    v2[s] = fminf(v2[s], sp);
                    kf[s] = lt ? kcol : kf[s];
                    v1[s] = fminf(v1[s], u);
                }
            }
        }
    }

    // Merge top-2 across the 16 lanes of each col-class (butterfly, width 16).
#pragma unroll
    for (int m = 1; m < 16; m <<= 1) {
#pragma unroll
        for (int s = 0; s < 8; ++s) {
            float ov1 = __shfl_xor(v1[s], m, 16);
            float okf = __shfl_xor(kf[s], m, 16);
            float ov2 = __shfl_xor(v2[s], m, 16);
            float nmx = fmaxf(v1[s], ov1);
            v2[s] = fminf(fminf(v2[s], ov2), nmx);
            bool lt = ov1 < v1[s];
            kf[s] = lt ? okf : kf[s];
            v1[s] = fminf(v1[s], ov1);
        }
    }
    if (l15 == 0) {
#pragma unroll
        for (int g = 0; g < 2; ++g)
#pragma unroll
            for (int rg = 0; rg < 4; ++rg) {
                const int s = 4 * g + rg;
                const int r = 32 * w + 16 * g + 4 * q + rg;
                kwin[r] = (int)kf[s];
                if (v2[s] <= v1[s] + BAND) {    // near-tie (incl. exact ties)
                    int i = atomicAdd(&fbcnt, 1);
                    if (i < FB_MAX) fbrows[i] = r;
                }
            }
    }
    __syncthreads();

    // FALLBACK: np-exact full rescan for near-tie rows (~1%). Uniform skip.
    const int cnt = min(fbcnt, FB_MAX);
    if (cnt > 0) {
        for (int i = tid; i < cnt * 64; i += 256) {
            int fi = i >> 6, l = i & 63;
            xfb[fi * 65 + l] = x[(size_t)b * DD * TT + (size_t)l * TT + t0 + fbrows[fi]];
        }
        u64 pmin[12];
#pragma unroll
        for (int sl = 0; sl < 12; ++sl) pmin[sl] = ~0ull;
#pragma unroll 1
        for (int T2 = 0; T2 < NT; ++T2) {
            __syncthreads();
            {   // stage f32 e tile, stride 65 (chain reads conflict-free)
                const int n = tid >> 2, qd = (tid & 3) * 16;
                const float* sp = emb + (size_t)(T2 * 64 + n) * DD + qd;
                float* dp = efs + n * 65 + qd;
#pragma unroll
                for (int j = 0; j < 16; ++j) dp[j] = sp[j];
            }
            __syncthreads();
#pragma unroll
            for (int sl = 0; sl < 12; ++sl) {
                const int fi = w + 4 * sl;
                if (fi < cnt) {
                    float acc = 0.0f;
#pragma unroll
                    for (int i = 0; i < 64; ++i)   // np-exact seq-k chain
                        acc = __builtin_fmaf(efs[lane * 65 + i], xfb[fi * 65 + i], acc);
                    float ck = Srow[fbrows[fi]] + e2l[T2 * 64 + lane];
                    float u = __builtin_fmaf(-2.0f, acc, ck);
                    u64 pk = ((u64)flipf(u) << 10) | (unsigned)(T2 * 64 + lane);
                    pmin[sl] = pmin[sl] < pk ? pmin[sl] : pk;
                }
            }
        }
#pragma unroll
        for (int sl = 0; sl < 12; ++sl) {
            const int fi = w + 4 * sl;
            if (fi < cnt) {
                u64 pk = pmin[sl];
#pragma unroll
                for (int dl = 32; dl > 0; dl >>= 1) {
                    u64 o = __shfl_xor(pk, dl);
                    pk = o < pk ? o : pk;
                }
                if (lane == 0) kwin[fbrows[fi]] = (int)(pk & 1023u);
            }
        }
        __syncthreads();
    }

    // Epilogue: idx, quant_out = emb[kwin] (exact), loss sum.
    if (tid < RPB) out[NELEM + 2 + row0 + tid] = (float)kwin[tid];

    const int r = tid & 127, c0 = (tid >> 7) * 32;
    const int kw = kwin[r];
    const float* eqr = emb + (size_t)kw * DD;
    float lsum = 0.0f;
#pragma unroll 8
    for (int i = 0; i < 32; ++i) {
        const int c = c0 + i;
        const size_t o = (size_t)b * DD * TT + (size_t)c * TT + t0 + r;
        float qv = eqr[c];
        float xv = x[o];
        out[o] = qv;
        float a = qv - xv;
        lsum = __builtin_fmaf(a, a, lsum);
    }
#pragma unroll
    for (int off = 32; off > 0; off >>= 1) lsum += __shfl_down(lsum, off);
    if (lane == 0) atomicAdd(&bsum, lsum);
    __syncthreads();
    if (tid == 0) atomicAdd(ws + WS_LOSS, bsum);
}

__global__ void vq_finalize(const float* __restrict__ ws, float* __restrict__ out) {
    if (threadIdx.x == 0 && blockIdx.x == 0) {
        float M = ws[WS_LOSS] / (float)NELEM;
        out[NELEM + 0] = M;           // codebook_loss
        out[NELEM + 1] = 0.25f * M;   // commitment_loss = BETA * same mean
    }
}

extern "C" void kernel_launch(void* const* d_in, const int* in_sizes, int n_in,
                              void* d_out, int out_size, void* d_ws, size_t ws_size,
                              hipStream_t stream) {
    const float* x = (const float*)d_in[0];
    const float* emb = (const float*)d_in[1];
    float* out = (float*)d_out;
    float* ws = (float*)d_ws;

    vq_prep<<<KCB / 4, 256, 0, stream>>>(emb, ws);
    vq_main<<<BT / RPB, 256, 0, stream>>>(x, emb, out, ws);
    vq_finalize<<<1, 64, 0, stream>>>(ws, out);
}